// Round 7
// baseline (123.496 us; speedup 1.0000x reference)
//
#include <hip/hip_runtime.h>

// NCN recurrence, 2 layers. B=4, N=4096, E=128, NK=4, ce=32, CACHE=32, m=128.
// 2048 independent [32 x 32] subproblems; one single-wave block each.
// Lane (h,o) owns feats [h*16,h*16+16) of row o as 8x float2 (packed VOP3P).
//
// R7 CORRECTNESS FIX: R6 failed post-timing revalidation because layer 1 ran
// IN-PLACE on d_out (read+write) -> the dispatch is not idempotent; any
// re-execution (profiler counter-group replay / graph warmup) corrupts the
// output. Now: layer 0 reads d_in -> writes d_ws; layer 1 reads d_ws ->
// writes d_out. Every dispatch is a pure input->output function.
//
// Scan step: sim(i) = di + dj with di = dot32(own row, Wi) via one
// shfl_xor(32); dj = dot32(row j, Wj) via two bpermutes of per-lane partials
// (issued BEFORE the 16 xj bpermutes so their latency overlaps); row-j slice
// via 16 bpermutes (no LDS buffer, no barrier).
// Weights pre-scaled by L1=log2(e); tanh via 0.1*F = 0.1 - 0.2/(exp2(arg)+1),
// arg = L1*xi + (L1*sim)*xj, unclamped (exp2 over/underflow -> exact +-1).

namespace {
constexpr int kB = 4;
constexpr int kN = 4096;
constexpr int kE = 128;
constexpr int kCE = 32;          // E / NK
constexpr int kH  = 16;          // feats per lane
constexpr int kQ  = kH / 2;      // float2 count
constexpr int kCache = 32;
constexpr int kM = kN / kCache;  // 128 groups per batch

typedef __attribute__((ext_vector_type(2))) float f32x2;

__device__ __forceinline__ f32x2 pk_fma(f32x2 a, f32x2 b, f32x2 c) {
    return __builtin_elementwise_fma(a, b, c);
}
}  // namespace

__global__ void ncn_layer_kernel(
    const float* __restrict__ x_in, const float* __restrict__ xa_in,
    const float* __restrict__ Wl,   // this layer's 256 floats
    float* __restrict__ x_out, float* __restrict__ xa_out,
    int s)                          // group stride: 0 for stage 0, 1 for stage 1
{
    const int blk = blockIdx.x;         // ((b*128 + g)*4 + n)
    const int n   = blk & 3;
    const int g   = (blk >> 2) & (kM - 1);
    const int b   = blk >> 9;
    const int t   = threadIdx.x;        // 0..63
    const int o   = t & 31;
    const int h   = t >> 5;

    // row index: ((g + o*s) % m) * CACHE + o
    const int r = (((g + o * s) & (kM - 1)) << 5) + o;
    const size_t base = ((size_t)(b * kN + r)) * kE + n * kCE + h * kH;

    constexpr float L1 = 1.4426950408889634f;   // log2(e)

    f32x2 xi[kQ], xa[kQ], wi[kQ], wj[kQ];

    {
        const float4* xi4 = reinterpret_cast<const float4*>(x_in + base);
        const float4* xa4 = reinterpret_cast<const float4*>(xa_in + base);
        const float4* wi4 = reinterpret_cast<const float4*>(Wl + n * kCE + h * kH);
        const float4* wj4 = reinterpret_cast<const float4*>(Wl + kE + n * kCE + h * kH);
#pragma unroll
        for (int q = 0; q < kQ / 2; ++q) {
            float4 v = xi4[q];
            xi[2 * q + 0] = f32x2{v.x, v.y}; xi[2 * q + 1] = f32x2{v.z, v.w};
            float4 a = xa4[q];
            xa[2 * q + 0] = f32x2{a.x, a.y}; xa[2 * q + 1] = f32x2{a.z, a.w};
            float4 u = wi4[q];   // pre-scale by L1: dots yield L1*sim directly
            wi[2 * q + 0] = f32x2{u.x * L1, u.y * L1};
            wi[2 * q + 1] = f32x2{u.z * L1, u.w * L1};
            float4 w = wj4[q];
            wj[2 * q + 0] = f32x2{w.x * L1, w.y * L1};
            wj[2 * q + 1] = f32x2{w.z * L1, w.w * L1};
        }
    }

    // bpermute byte-address base for xj pulls: source lane (t & 32) + j
    const int srcbase = (t & 32) * 4;

#pragma unroll 2
    for (int j = 0; j < kCache; ++j) {
        const int srcaddr = srcbase + j * 4;

        // (1) own-row dots first: part = dot16(xi,wi), pj = dot16(xi,wj)
        f32x2 a01 = xi[0] * wi[0];
        f32x2 a23 = xi[1] * wi[1];
        f32x2 b01 = xi[0] * wj[0];
        f32x2 b23 = xi[1] * wj[1];
#pragma unroll
        for (int q = 2; q < kQ; q += 2) {
            a01 = pk_fma(xi[q + 0], wi[q + 0], a01);
            a23 = pk_fma(xi[q + 1], wi[q + 1], a23);
            b01 = pk_fma(xi[q + 0], wj[q + 0], b01);
            b23 = pk_fma(xi[q + 1], wj[q + 1], b23);
        }
        f32x2 av = a01 + a23;
        f32x2 bv = b01 + b23;
        float part = av.x + av.y;     // L1 * dot16(row i, Wi-half)
        float pj   = bv.x + bv.y;     // L1 * dot16(row i, Wj-half)

        // (2) cross-lane for sim: issue early so latency overlaps xj pulls
        float di_o = __shfl_xor(part, 32, 64);
        float dj0  = __int_as_float(
            __builtin_amdgcn_ds_bpermute(j * 4, __float_as_int(pj)));
        float dj1  = __int_as_float(
            __builtin_amdgcn_ds_bpermute(128 + j * 4, __float_as_int(pj)));

        // (3) row-j slice pull — 16 independent bpermutes
        f32x2 xj[kQ];
#pragma unroll
        for (int q = 0; q < kQ; ++q) {
            xj[q].x = __int_as_float(
                __builtin_amdgcn_ds_bpermute(srcaddr, __float_as_int(xi[q].x)));
            xj[q].y = __int_as_float(
                __builtin_amdgcn_ds_bpermute(srcaddr, __float_as_int(xi[q].y)));
        }

        const float sim = (part + di_o) + (dj0 + dj1);  // = L1 * sim_true
        const f32x2 sv  = {sim, sim};
        const f32x2 l12 = {L1, L1};
        const f32x2 one = {1.0f, 1.0f};
        const f32x2 m02 = {-0.2f, -0.2f};
        const f32x2 c9  = {0.9f, 0.9f};
        const f32x2 c01 = {0.1f, 0.1f};

#pragma unroll
        for (int q = 0; q < kQ; ++q) {
            f32x2 arg = pk_fma(xj[q], sv, xi[q] * l12);  // 2*L1*T
            f32x2 t2;
            t2.x = __builtin_amdgcn_exp2f(arg.x);
            t2.y = __builtin_amdgcn_exp2f(arg.y);
            f32x2 den = t2 + one;
            f32x2 rc;
            rc.x = __builtin_amdgcn_rcpf(den.x);
            rc.y = __builtin_amdgcn_rcpf(den.y);
            // xa' = 0.9*xa + 0.1*tanh = (0.9*xa + 0.1) - 0.2*rc
            xa[q] = pk_fma(m02, rc, pk_fma(c9, xa[q], c01));
            // xi' = 0.9*xi + 0.1*xa'
            xi[q] = pk_fma(c01, xa[q], xi[q] * c9);
        }
    }

    {
        float4* xo4 = reinterpret_cast<float4*>(x_out + base);
        float4* ao4 = reinterpret_cast<float4*>(xa_out + base);
#pragma unroll
        for (int q = 0; q < kQ / 2; ++q) {
            float4 v;
            v.x = xi[2 * q + 0].x; v.y = xi[2 * q + 0].y;
            v.z = xi[2 * q + 1].x; v.w = xi[2 * q + 1].y;
            xo4[q] = v;
            float4 a;
            a.x = xa[2 * q + 0].x; a.y = xa[2 * q + 0].y;
            a.z = xa[2 * q + 1].x; a.w = xa[2 * q + 1].y;
            ao4[q] = a;
        }
    }
}

extern "C" void kernel_launch(void* const* d_in, const int* in_sizes, int n_in,
                              void* d_out, int out_size, void* d_ws, size_t ws_size,
                              hipStream_t stream) {
    const float* x  = (const float*)d_in[0];   // [B, N, E] fp32
    const float* xa = (const float*)d_in[1];   // [B, N, E] fp32
    const float* W  = (const float*)d_in[2];   // [2, 256] fp32

    const size_t plane = (size_t)kB * kN * kE;   // 2,097,152 floats

    float* x_mid  = (float*)d_ws;                // layer-0 outputs in workspace
    float* xa_mid = x_mid + plane;               // (32 MB total, ws is larger)

    float* x_out  = (float*)d_out;               // final outputs
    float* xa_out = x_out + plane;

    const dim3 grid(kB * kM * 4);   // 2048 single-wave blocks
    const dim3 block(64);

    // Layer 0 (stage 0, s = 0): d_in -> ws       (pure, idempotent)
    ncn_layer_kernel<<<grid, block, 0, stream>>>(x, xa, W, x_mid, xa_mid, 0);
    // Layer 1 (stage 1, s = 1): ws -> d_out      (pure, idempotent)
    ncn_layer_kernel<<<grid, block, 0, stream>>>(x_mid, xa_mid, W + 2 * kE,
                                                 x_out, xa_out, 1);
}